// Round 1
// baseline (65.069 us; speedup 1.0000x reference)
//
#include <hip/hip_runtime.h>

// TrainableButterfly: LENGTH=2048 (11 levels), BATCH=4096.
// CROSS_T=1.0, CROSS_PHI=0.0 -> crossings are identity; only permutations matter.
// Composing bitrev with the per-level gathers: storage map
//   sigma_l(i) = ((i mod 2^{l+1}) << (10-l)) | rev_{10-l}(i >> (l+1))
// => in natural storage order, level l is a butterfly on slots (s, s+2^{10-l}),
//    in place, and after level 10 the array is in natural (output) order.
// Twiddle pair index for storage slot s at level l:
//   p(s,l) = (rev_{10-l}(s & (2^{10-l}-1)) << l) | (s >> (11-l))
// Twiddles are precomputed in storage order so the main kernel does zero index math.

#define NLEV 11

__device__ __forceinline__ unsigned revw(unsigned x, int w) {
    return w ? (__brev(x) >> (32 - w)) : 0u;
}

// d_ws layout in float4 units:
//   [0, 1024)            level-0 table, indexed by storage slot s (pairs (s, s+1024))
//   [1024 + f*2048 + u*4 + m)  fused tables for stages f=0..4 covering levels (2f+1, 2f+2)
//        m=0: lvl l @ s ; m=1: lvl l @ s+h ; m=2: lvl l+1 @ s ; m=3: lvl l+1 @ s+2h
//   [11264, 12288)       final pointwise table ps (2 complex per float4)
__global__ void twiddle_kernel(const float* __restrict__ phases, float4* __restrict__ tw) {
    int id = blockIdx.x * 256 + threadIdx.x;
    if (id < 1024) {
        unsigned s = id;
        unsigned p = revw(s, 10);                  // level 0: p = rev10(s)
        float t1 = phases[p * 2 + 0], t2 = phases[p * 2 + 1];
        tw[id] = make_float4(cosf(t1), sinf(t1), cosf(t2), sinf(t2));
    } else if (id < 11264) {
        int j = id - 1024;
        int f = j >> 11;
        int rem = j & 2047;
        int u = rem >> 2;
        int m = rem & 3;
        int l0 = 2 * f + 1;
        int level = l0 + (m >> 1);
        unsigned h = 1u << (9 - l0);
        unsigned s = (((unsigned)u >> (9 - l0)) << (11 - l0)) | ((unsigned)u & (h - 1));
        if (m == 1) s += h;
        if (m == 3) s += 2 * h;
        int shift = 10 - level;
        unsigned p = (revw(s & ((1u << shift) - 1u), shift) << level) | (s >> (shift + 1));
        const float* ph = phases + (level * 1024 + p) * 2;
        float t1 = ph[0], t2 = ph[1];
        tw[id] = make_float4(cosf(t1), sinf(t1), cosf(t2), sinf(t2));
    } else if (id < 12288) {
        int q = id - 11264;
        const float* lp = phases + 11 * 2048 + q * 2;  // phases[-1] flattened
        float a = lp[0], b = lp[1];
        tw[id] = make_float4(cosf(a), sinf(a), cosf(b), sinf(b));
    }
}

// butterfly: o0 = e^{i t1} v0 + i e^{i t2} v1 ; o1 = i e^{i t1} v0 + e^{i t2} v1
// w = (cos t1, sin t1, cos t2, sin t2)
__device__ __forceinline__ void bf(float2 v0, float2 v1, float4 w, float2& o0, float2& o1) {
    float ar = fmaf(w.x, v0.x, -w.y * v0.y);
    float ai = fmaf(w.x, v0.y,  w.y * v0.x);
    float br = fmaf(w.z, v1.x, -w.w * v1.y);
    float bi = fmaf(w.z, v1.y,  w.w * v1.x);
    o0 = make_float2(ar - bi, ai + br);
    o1 = make_float2(br - ai, bi + ar);
}

// LDS: 2048 complex per row as 1024 float4 units, XOR-swizzled within 128B windows.
__device__ __forceinline__ unsigned swz(unsigned U) { return U ^ ((U >> 3) & 7u); }
__device__ __forceinline__ float2 ld2(const float4* lds, unsigned e) {
    return ((const float2*)lds)[swz(e >> 1) * 2 + (e & 1)];
}
__device__ __forceinline__ void st2(float4* lds, unsigned e, float2 v) {
    ((float2*)lds)[swz(e >> 1) * 2 + (e & 1)] = v;
}

// Fused pair of levels (L, L+1), strides d=2^{10-L}, d/2. Radix-4 in registers, in place.
template <int L>
__device__ __forceinline__ void fused_stage(float4* lds, const float4* __restrict__ tw, int t) {
    constexpr unsigned h = 1u << (9 - L);              // = d/2
    constexpr int fbase = 1024 + ((L - 1) / 2) * 2048;
#pragma unroll
    for (int g = 0; g < 2; ++g) {
        unsigned u = t + 256 * g;
        unsigned s = ((u >> (9 - L)) << (11 - L)) | (u & (h - 1));
        float2 e0 = ld2(lds, s);
        float2 e1 = ld2(lds, s + h);
        float2 e2 = ld2(lds, s + 2 * h);
        float2 e3 = ld2(lds, s + 3 * h);
        float4 w0 = tw[fbase + 4 * u + 0];
        float4 w1 = tw[fbase + 4 * u + 1];
        float4 w2 = tw[fbase + 4 * u + 2];
        float4 w3 = tw[fbase + 4 * u + 3];
        float2 a0, a1, a2, a3, b0, b1, b2, b3;
        bf(e0, e2, w0, a0, a2);   // level L:   (s,     s+2h)
        bf(e1, e3, w1, a1, a3);   // level L:   (s+h,   s+3h)
        bf(a0, a1, w2, b0, b1);   // level L+1: (s,     s+h)
        bf(a2, a3, w3, b2, b3);   // level L+1: (s+2h,  s+3h)
        st2(lds, s, b0);
        st2(lds, s + h, b1);
        st2(lds, s + 2 * h, b2);
        st2(lds, s + 3 * h, b3);
    }
}

__global__ __launch_bounds__(256) void bfly_kernel(const float4* __restrict__ x,
                                                   const float4* __restrict__ tw,
                                                   float4* __restrict__ out) {
    __shared__ float4 lds[1024];
    const int t = threadIdx.x;
    const int rowbase = blockIdx.x * 1024;   // float4 units per row

    // Stage A: global load (coalesced) + level 0 (pairs (s, s+1024)) -> LDS
#pragma unroll
    for (int k = 0; k < 2; ++k) {
        unsigned v = t + 256 * k;                 // float4 unit in [0,512)
        float4 q0 = x[rowbase + v];               // elements 2v, 2v+1
        float4 q1 = x[rowbase + v + 512];         // elements 2v+1024, 2v+1025
        float4 w0 = tw[2 * v], w1 = tw[2 * v + 1];
        float2 o0a, o1a, o0b, o1b;
        bf(make_float2(q0.x, q0.y), make_float2(q1.x, q1.y), w0, o0a, o1a);
        bf(make_float2(q0.z, q0.w), make_float2(q1.z, q1.w), w1, o0b, o1b);
        lds[swz(v)]       = make_float4(o0a.x, o0a.y, o0b.x, o0b.y);
        lds[swz(v + 512)] = make_float4(o1a.x, o1a.y, o1b.x, o1b.y);
    }
    __syncthreads();

    fused_stage<1>(lds, tw, t);  __syncthreads();   // levels 1,2
    fused_stage<3>(lds, tw, t);  __syncthreads();   // levels 3,4
    fused_stage<5>(lds, tw, t);  __syncthreads();   // levels 5,6
    fused_stage<7>(lds, tw, t);  __syncthreads();   // levels 7,8

    // Stage F: levels 9,10 + final pointwise multiply + coalesced global store
    constexpr int fbase = 1024 + 4 * 2048;  // 9216
#pragma unroll
    for (int g = 0; g < 2; ++g) {
        unsigned u = t + 256 * g;                 // group: elements 4u..4u+3
        float4 q0 = lds[swz(2 * u)];              // elements 4u, 4u+1
        float4 q1 = lds[swz(2 * u + 1)];          // elements 4u+2, 4u+3
        float4 w0 = tw[fbase + 4 * u + 0];
        float4 w1 = tw[fbase + 4 * u + 1];
        float4 w2 = tw[fbase + 4 * u + 2];
        float4 w3 = tw[fbase + 4 * u + 3];
        float2 a0, a1, a2, a3, b0, b1, b2, b3;
        bf(make_float2(q0.x, q0.y), make_float2(q1.x, q1.y), w0, a0, a2); // lvl9 (4u, 4u+2)
        bf(make_float2(q0.z, q0.w), make_float2(q1.z, q1.w), w1, a1, a3); // lvl9 (4u+1, 4u+3)
        bf(a0, a1, w2, b0, b1);                                           // lvl10 (4u, 4u+1)
        bf(a2, a3, w3, b2, b3);                                           // lvl10 (4u+2, 4u+3)
        float4 p0 = tw[11264 + 2 * u];
        float4 p1 = tw[11264 + 2 * u + 1];
        out[rowbase + 2 * u] = make_float4(
            fmaf(p0.x, b0.x, -p0.y * b0.y), fmaf(p0.x, b0.y, p0.y * b0.x),
            fmaf(p0.z, b1.x, -p0.w * b1.y), fmaf(p0.z, b1.y, p0.w * b1.x));
        out[rowbase + 2 * u + 1] = make_float4(
            fmaf(p1.x, b2.x, -p1.y * b2.y), fmaf(p1.x, b2.y, p1.y * b2.x),
            fmaf(p1.z, b3.x, -p1.w * b3.y), fmaf(p1.z, b3.y, p1.w * b3.x));
    }
}

extern "C" void kernel_launch(void* const* d_in, const int* in_sizes, int n_in,
                              void* d_out, int out_size, void* d_ws, size_t ws_size,
                              hipStream_t stream) {
    const float* x = (const float*)d_in[0];        // (4096, 2048, 2) f32
    const float* phases = (const float*)d_in[1];   // (12, 1024, 2) f32
    float4* tw = (float4*)d_ws;                    // needs 192 KB

    twiddle_kernel<<<48, 256, 0, stream>>>(phases, tw);
    bfly_kernel<<<4096, 256, 0, stream>>>((const float4*)x, tw, (float4*)d_out);
}

// Round 2
// 40.124 us; speedup vs baseline: 1.6217x; 1.6217x over previous
//
#include <hip/hip_runtime.h>

// TrainableButterfly: LENGTH=2048 (11 levels), BATCH=4096.
// CROSS_T=1.0, CROSS_PHI=0.0 -> crossings are identity permutations; composing
// bitrev with the per-level gathers gives, in natural storage order:
//   level l = butterfly on slots (s, s + 2^{10-l}), in place; final order = natural.
// Twiddle pair index for storage slot s at level l:
//   p(s,l) = (rev_{10-l}(s & (2^{10-l}-1)) << l) | (s >> (11-l))
//
// This version: 2 rows/block (twiddle reuse + ILP), radix-8 register stages
// for levels 1-3 / 4-6 / 7-9, level 10 fused into the coalesced store.
//
// d_ws float4 layout (192 KB):
//   [0,1024)       A-table: level-0 twiddle for pair slot s
//   [1024,10240)   3 stage tables (3072 each): base + m*256 + u, m in [0,12)
//   [10240,11264)  F-table: level-10 twiddle for pair (2v, 2v+1)
//   [11264,12288)  P-table: pointwise e^{i lp}, 2 complex per float4

__device__ __forceinline__ unsigned revw(unsigned x, int w) {
    return w ? (__brev(x) >> (32 - w)) : 0u;
}

__global__ void twiddle_kernel(const float* __restrict__ phases, float4* __restrict__ tw) {
    int id = blockIdx.x * 256 + threadIdx.x;
    float t1, t2;
    if (id < 1024) {
        unsigned p = revw((unsigned)id, 10);           // level 0
        t1 = phases[p * 2 + 0]; t2 = phases[p * 2 + 1];
    } else if (id < 10240) {
        int j = id - 1024;
        int sg = j / 3072;            // stage 0..2 -> levels 3sg+1 .. 3sg+3
        int rem = j % 3072;
        int m = rem >> 8;             // 0..11
        int u = rem & 255;
        int L = 3 * sg + 1;
        int lvl_off = m >> 2;         // 0,1,2
        int pj = m & 3;
        int c;                        // lower-slot coefficient (in units of h)
        if (lvl_off == 0) c = pj;                      // pairs (j, j+4)
        else if (lvl_off == 1) c = (pj & 1) | ((pj >> 1) << 2);  // {0,1,4,5}
        else c = pj << 1;                              // {0,2,4,6}
        unsigned h = 1u << (8 - L);
        unsigned s = (((unsigned)u >> (8 - L)) << (11 - L)) | ((unsigned)u & (h - 1));
        unsigned slot = s + (unsigned)c * h;
        int level = L + lvl_off;
        int shift = 10 - level;
        unsigned p = (revw(slot & ((1u << shift) - 1u), shift) << level) | (slot >> (shift + 1));
        const float* ph = phases + (level * 1024 + p) * 2;
        t1 = ph[0]; t2 = ph[1];
    } else if (id < 11264) {
        unsigned v = id - 10240;      // level 10: pair (2v,2v+1), p = v
        const float* ph = phases + (10 * 1024 + v) * 2;
        t1 = ph[0]; t2 = ph[1];
    } else if (id < 12288) {
        int q = id - 11264;
        const float* lp = phases + 11 * 2048 + q * 2;  // phases[-1] flat
        t1 = lp[0]; t2 = lp[1];
    } else {
        return;
    }
    tw[id] = make_float4(cosf(t1), sinf(t1), cosf(t2), sinf(t2));
}

// butterfly: o0 = e^{i t1} v0 + i e^{i t2} v1 ; o1 = i e^{i t1} v0 + e^{i t2} v1
__device__ __forceinline__ void bf(float2 v0, float2 v1, float4 w, float2& o0, float2& o1) {
    float ar = fmaf(w.x, v0.x, -w.y * v0.y);
    float ai = fmaf(w.x, v0.y,  w.y * v0.x);
    float br = fmaf(w.z, v1.x, -w.w * v1.y);
    float bi = fmaf(w.z, v1.y,  w.w * v1.x);
    o0 = make_float2(ar - bi, ai + br);
    o1 = make_float2(br - ai, bi + ar);
}

__device__ __forceinline__ unsigned swz(unsigned U) { return U ^ ((U >> 3) & 7u); }
__device__ __forceinline__ float2 ld2(const float4* lds, unsigned e) {
    return ((const float2*)lds)[swz(e >> 1) * 2 + (e & 1)];
}
__device__ __forceinline__ void st2(float4* lds, unsigned e, float2 v) {
    ((float2*)lds)[swz(e >> 1) * 2 + (e & 1)] = v;
}

// radix-8 over levels L, L+1, L+2 on e[0..7] (slots s + j*h), in place
__device__ __forceinline__ void radix8_compute(float2 e[8], const float4 W[12]) {
    float2 a[8], b[8];
    bf(e[0], e[4], W[0], a[0], a[4]);
    bf(e[1], e[5], W[1], a[1], a[5]);
    bf(e[2], e[6], W[2], a[2], a[6]);
    bf(e[3], e[7], W[3], a[3], a[7]);
    bf(a[0], a[2], W[4], b[0], b[2]);
    bf(a[1], a[3], W[5], b[1], b[3]);
    bf(a[4], a[6], W[6], b[4], b[6]);
    bf(a[5], a[7], W[7], b[5], b[7]);
    bf(b[0], b[1], W[8],  e[0], e[1]);
    bf(b[2], b[3], W[9],  e[2], e[3]);
    bf(b[4], b[5], W[10], e[4], e[5]);
    bf(b[6], b[7], W[11], e[6], e[7]);
}

template <int L>
__device__ __forceinline__ void radix8_stage(float4* l0, float4* l1,
                                             const float4* __restrict__ tw, int t) {
    constexpr unsigned h = 1u << (8 - L);
    constexpr int base = 1024 + ((L - 1) / 3) * 3072;
    const unsigned u = (unsigned)t;
    const unsigned s = ((u >> (8 - L)) << (11 - L)) | (u & (h - 1));
    float4 W[12];
#pragma unroll
    for (int m = 0; m < 12; ++m) W[m] = tw[base + m * 256 + u];   // lane-coalesced
    float2 e0[8], e1[8];
#pragma unroll
    for (int j = 0; j < 8; ++j) e0[j] = ld2(l0, s + j * h);
#pragma unroll
    for (int j = 0; j < 8; ++j) e1[j] = ld2(l1, s + j * h);
    radix8_compute(e0, W);
    radix8_compute(e1, W);
#pragma unroll
    for (int j = 0; j < 8; ++j) st2(l0, s + j * h, e0[j]);
#pragma unroll
    for (int j = 0; j < 8; ++j) st2(l1, s + j * h, e1[j]);
}

__global__ __launch_bounds__(256) void bfly_kernel(const float4* __restrict__ x,
                                                   const float4* __restrict__ tw,
                                                   float4* __restrict__ out) {
    __shared__ float4 lds[2048];          // 2 rows x 1024 float4 = 32 KB
    const int t = threadIdx.x;
    const int rowbase = blockIdx.x * 2048;  // float4 units (2 rows/block)
    float4* l0 = lds;
    float4* l1 = lds + 1024;

    // Stage A: global load + level 0 (pairs (s, s+1024)) -> LDS
#pragma unroll
    for (int k = 0; k < 2; ++k) {
        unsigned v = (unsigned)t + 256u * k;       // float4 unit in [0,512)
        float4 w0 = tw[2 * v], w1 = tw[2 * v + 1]; // shared by both rows
#pragma unroll
        for (int r = 0; r < 2; ++r) {
            const float4* xr = x + rowbase + r * 1024;
            float4 q0 = xr[v];
            float4 q1 = xr[v + 512];
            float2 o0a, o1a, o0b, o1b;
            bf(make_float2(q0.x, q0.y), make_float2(q1.x, q1.y), w0, o0a, o1a);
            bf(make_float2(q0.z, q0.w), make_float2(q1.z, q1.w), w1, o0b, o1b);
            float4* lr = r ? l1 : l0;
            lr[swz(v)]       = make_float4(o0a.x, o0a.y, o0b.x, o0b.y);
            lr[swz(v + 512)] = make_float4(o1a.x, o1a.y, o1b.x, o1b.y);
        }
    }
    __syncthreads();

    radix8_stage<1>(l0, l1, tw, t); __syncthreads();   // levels 1,2,3
    radix8_stage<4>(l0, l1, tw, t); __syncthreads();   // levels 4,5,6
    radix8_stage<7>(l0, l1, tw, t); __syncthreads();   // levels 7,8,9

    // Stage F: level 10 (intra-unit pairs (2v,2v+1)) + pointwise + coalesced store
#pragma unroll
    for (int g = 0; g < 4; ++g) {
        unsigned v = (unsigned)t + 256u * g;
        float4 wf = tw[10240 + v];
        float4 wp = tw[11264 + v];
#pragma unroll
        for (int r = 0; r < 2; ++r) {
            float4 q = (r ? l1 : l0)[swz(v)];
            float2 o0, o1;
            bf(make_float2(q.x, q.y), make_float2(q.z, q.w), wf, o0, o1);
            out[rowbase + r * 1024 + v] = make_float4(
                fmaf(wp.x, o0.x, -wp.y * o0.y), fmaf(wp.x, o0.y, wp.y * o0.x),
                fmaf(wp.z, o1.x, -wp.w * o1.y), fmaf(wp.z, o1.y, wp.w * o1.x));
        }
    }
}

extern "C" void kernel_launch(void* const* d_in, const int* in_sizes, int n_in,
                              void* d_out, int out_size, void* d_ws, size_t ws_size,
                              hipStream_t stream) {
    const float* x = (const float*)d_in[0];        // (4096, 2048, 2) f32
    const float* phases = (const float*)d_in[1];   // (12, 1024, 2) f32
    float4* tw = (float4*)d_ws;                    // 192 KB

    twiddle_kernel<<<48, 256, 0, stream>>>(phases, tw);
    bfly_kernel<<<2048, 256, 0, stream>>>((const float4*)x, tw, (float4*)d_out);
}